// Round 1
// baseline (10335.175 us; speedup 1.0000x reference)
//
#include <hip/hip_runtime.h>
#include <hip/hip_bf16.h>
#include <math.h>

// LPCDARTS forward on MI355X.
// Strategy: collapse all 9 conv-type ops per edge into ONE dense 9x9 conv with
// combined weights Wc[e][o][c][9][9] built on-device from softmax(arch)/raw
// weights. Pools (max/avg 3x3 over full 256ch) fused per node with acc init.
//
// Layout: all states are (64, 256, 32, 32) fp32. Gathered edge inputs are
// states[i][:, idx[e]] -- the gather is folded into the conv's channel
// indexing; the scatter acc[:, idx[e]] += p is folded into the output write.

#define NB 64      // batch
#define CF 256     // full channels
#define PC 64      // gathered channels
#define HW 32
#define NEDGE 10
#define KR 4       // conv radius (9x9)
#define KW 9
#define TAPS 81

// ---------------- softmax over arch params (10 edges x 12 ops) -------------
__global__ void softmax_kernel(const float* __restrict__ arch,
                               const float* __restrict__ norms,
                               float* __restrict__ sw) {
    int e = threadIdx.x;
    if (e >= NEDGE) return;
    // map edge -> (node, i)
    int node = 0, i = e;
    while (i > node) { i -= node + 1; node++; }
    float norm = fmaxf(norms[node * 5 + i], 1e-5f);
    const float* a = arch + (node * 5 + i) * 12;
    float v[12];
    float m = -3.0e38f;
    for (int k = 0; k < 12; ++k) { v[k] = a[k] / norm; m = fmaxf(m, v[k]); }
    float ssum = 0.f;
    for (int k = 0; k < 12; ++k) { v[k] = expf(v[k] - m); ssum += v[k]; }
    float inv = 1.0f / ssum;
    for (int k = 0; k < 12; ++k) sw[e * 12 + k] = v[k] * inv;
}

// ---------------- build combined 9x9 weights -------------------------------
// Wc[e][o][c][tap], tap = (dy+4)*9 + (dx+4)
__global__ void build_w(const float* __restrict__ w3, const float* __restrict__ w5,
                        const float* __restrict__ w7, const float* __restrict__ w1,
                        const float* __restrict__ s3dw, const float* __restrict__ s3pw,
                        const float* __restrict__ s5dw, const float* __restrict__ s5pw,
                        const float* __restrict__ d3, const float* __restrict__ d5,
                        const float* __restrict__ sw, float* __restrict__ Wc) {
    int gid = blockIdx.x * 256 + threadIdx.x;  // total = 10*64*64*81 = 3,317,760
    int tap = gid % TAPS;
    int rc  = gid / TAPS;
    int c = rc & 63;
    int ro = rc >> 6;
    int o = ro & 63;
    int e = ro >> 6;
    int dy = tap / KW - KR, dx = tap % KW - KR;
    const float* w = sw + e * 12;
    int eoc = (e * 64 + o) * 64 + c;
    int ec  = e * 64 + c;
    float val = 0.f;
    int ady = dy < 0 ? -dy : dy, adx = dx < 0 ? -dx : dx;
    if (ady <= 1 && adx <= 1) {
        val += w[1] * w3[eoc * 9 + (dy + 1) * 3 + (dx + 1)];
        val += w[7] * s3pw[eoc] * s3dw[ec * 9 + (dy + 1) * 3 + (dx + 1)];
    }
    if (ady <= 2 && adx <= 2) {
        val += w[2] * w5[eoc * 25 + (dy + 2) * 5 + (dx + 2)];
        val += w[8] * s5pw[eoc] * s5dw[ec * 25 + (dy + 2) * 5 + (dx + 2)];
        if (((dy | dx) & 1) == 0)
            val += w[9] * d3[eoc * 9 + (dy / 2 + 1) * 3 + (dx / 2 + 1)];
    }
    if (ady <= 3 && adx <= 3)
        val += w[3] * w7[eoc * 49 + (dy + 3) * 7 + (dx + 3)];
    if (((dy | dx) & 1) == 0)
        val += w[10] * d5[eoc * 25 + (dy / 2 + 2) * 5 + (dx / 2 + 2)];
    if (dy == 0 && dx == 0) {
        val += w[4] * w1[eoc];
        if (o == c) val += w[0];
    }
    Wc[gid] = val;
}

// ---------------- pools: acc = sum_i w5_i*maxpool3(s_i) + w6_i*avgpool3(s_i)
// Also serves as the zero-init of acc (plain store).
__global__ void pool_node(const float* __restrict__ s0, const float* __restrict__ s1,
                          const float* __restrict__ s2, const float* __restrict__ s3,
                          float* __restrict__ acc, const float* __restrict__ sw,
                          int ebase, int nedges) {
    int gid = blockIdx.x * 256 + threadIdx.x;  // over 64*256*1024
    int x = gid & 31;
    int y = (gid >> 5) & 31;
    int plane = gid >> 10;  // (n*256 + c)
    const float* states[4] = {s0, s1, s2, s3};
    float val = 0.f;
    for (int i = 0; i < nedges; ++i) {
        const float* base = states[i] + (plane << 10);
        float mx = -3.0e38f;
        float sum = 0.f;
        #pragma unroll
        for (int dy = -1; dy <= 1; ++dy) {
            #pragma unroll
            for (int dx = -1; dx <= 1; ++dx) {
                int yy = y + dy, xx = x + dx;
                if ((unsigned)yy < 32u && (unsigned)xx < 32u) {
                    float v = base[yy * 32 + xx];
                    mx = fmaxf(mx, v);
                    sum += v;
                }
            }
        }
        val += sw[(ebase + i) * 12 + 5] * mx + sw[(ebase + i) * 12 + 6] * (sum * (1.0f / 9.0f));
    }
    acc[gid] = val;
}

// ---------------- combined 9x9 conv for one edge ---------------------------
// Block = (n, o): 256 threads, each computes a 4-row column of outputs.
// LDS: 40x40 zero-padded input tile for one gathered channel at a time.
#define TILE 40
__global__ __launch_bounds__(256) void conv_edge(const float* __restrict__ s,
                                                 float* __restrict__ acc,
                                                 const float* __restrict__ Wc,
                                                 const int* __restrict__ idx,
                                                 int e) {
    __shared__ float tile[TILE * TILE];
    __shared__ float wrow[TAPS];
    __shared__ int ids[PC];
    int t = threadIdx.x;
    int o = blockIdx.x & 63;
    int n = blockIdx.x >> 6;
    if (t < PC) ids[t] = idx[e * PC + t];
    __syncthreads();

    int x0 = t & 31;
    int y0 = (t >> 5) * 4;  // 0,4,...,28
    float a0 = 0.f, a1 = 0.f, a2 = 0.f, a3 = 0.f;
    const float* wbase = Wc + (size_t)((e * 64 + o) * 64) * TAPS;

    for (int c = 0; c < PC; ++c) {
        const float* sp = s + (size_t)(n * CF + ids[c]) * (HW * HW);
        // stage 40x40 zero-padded tile (1600 elems, 256 threads)
        for (int l = t; l < TILE * TILE; l += 256) {
            int ty = l / TILE, tx = l - ty * TILE;
            int gy = ty - KR, gx = tx - KR;
            float v = 0.f;
            if ((unsigned)gy < 32u && (unsigned)gx < 32u) v = sp[gy * 32 + gx];
            tile[l] = v;
        }
        if (t < TAPS) wrow[t] = wbase[c * TAPS + t];
        __syncthreads();

        #pragma unroll
        for (int dx = 0; dx < KW; ++dx) {
            float in[12];
            #pragma unroll
            for (int r = 0; r < 12; ++r) in[r] = tile[(y0 + r) * TILE + x0 + dx];
            #pragma unroll
            for (int dy = 0; dy < KW; ++dy) {
                float w = wrow[dy * KW + dx];
                a0 = fmaf(w, in[dy], a0);
                a1 = fmaf(w, in[dy + 1], a1);
                a2 = fmaf(w, in[dy + 2], a2);
                a3 = fmaf(w, in[dy + 3], a3);
            }
        }
        __syncthreads();
    }

    int oc = ids[o];
    float* op = acc + (size_t)(n * CF + oc) * (HW * HW) + y0 * 32 + x0;
    op[0]  += a0;
    op[32] += a1;
    op[64] += a2;
    op[96] += a3;
}

extern "C" void kernel_launch(void* const* d_in, const int* in_sizes, int n_in,
                              void* d_out, int out_size, void* d_ws, size_t ws_size,
                              hipStream_t stream) {
    const float* x    = (const float*)d_in[0];
    const float* arch = (const float*)d_in[1];
    const float* norms= (const float*)d_in[2];
    const int*   idx  = (const int*)d_in[3];
    const float* w3   = (const float*)d_in[4];
    const float* w5   = (const float*)d_in[5];
    const float* w7   = (const float*)d_in[6];
    const float* w1   = (const float*)d_in[7];
    const float* s3dw = (const float*)d_in[8];
    const float* s3pw = (const float*)d_in[9];
    const float* s5dw = (const float*)d_in[10];
    const float* s5pw = (const float*)d_in[11];
    const float* d3   = (const float*)d_in[12];
    const float* d5   = (const float*)d_in[13];
    float* out = (float*)d_out;

    const size_t S = (size_t)NB * CF * HW * HW;  // 16,777,216 floats
    float* st1 = (float*)d_ws;
    float* st2 = st1 + S;
    float* st3 = st2 + S;
    float* Wc  = st3 + S;                         // 10*64*64*81 = 3,317,760 floats
    float* sw  = Wc + (size_t)NEDGE * 64 * 64 * TAPS;

    softmax_kernel<<<1, 64, 0, stream>>>(arch, norms, sw);
    build_w<<<(NEDGE * 64 * 64 * TAPS) / 256, 256, 0, stream>>>(
        w3, w5, w7, w1, s3dw, s3pw, s5dw, s5pw, d3, d5, sw, Wc);

    float* states[5] = {(float*)x, st1, st2, st3, out};
    int e = 0;
    for (int node = 0; node < 4; ++node) {
        int ebase = node * (node + 1) / 2;
        // pools + acc init for this node
        pool_node<<<(int)(S / 256), 256, 0, stream>>>(
            states[0], states[1], states[2], states[3],
            states[node + 1], sw, ebase, node + 1);
        // one combined 9x9 conv per incoming edge (sequential => no atomics)
        for (int i = 0; i <= node; ++i) {
            conv_edge<<<NB * 64, 256, 0, stream>>>(states[i], states[node + 1], Wc, idx, e);
            ++e;
        }
    }
}

// Round 2
// 5200.611 us; speedup vs baseline: 1.9873x; 1.9873x over previous
//
#include <hip/hip_runtime.h>
#include <hip/hip_bf16.h>
#include <math.h>

// LPCDARTS forward on MI355X — v2.
// All 9 conv-type ops per edge collapsed into ONE dense 9x9 conv (combined
// weights Wc[e][o][c][81]). Conv v2: 8x-wide threads, ds_read_b128 inputs,
// scalar (SGPR) weight loads, packed-fp32 FMA via even/odd dx pairing.

#define NB 64      // batch
#define CF 256     // full channels
#define PC 64      // gathered channels
#define HW 32
#define NEDGE 10
#define KR 4       // conv radius (9x9)
#define KW 9
#define TAPS 81

typedef float f4v __attribute__((ext_vector_type(4)));
typedef float f2v __attribute__((ext_vector_type(2)));

// ---------------- softmax over arch params (10 edges x 12 ops) -------------
__global__ void softmax_kernel(const float* __restrict__ arch,
                               const float* __restrict__ norms,
                               float* __restrict__ sw) {
    int e = threadIdx.x;
    if (e >= NEDGE) return;
    int node = 0, i = e;
    while (i > node) { i -= node + 1; node++; }
    float norm = fmaxf(norms[node * 5 + i], 1e-5f);
    const float* a = arch + (node * 5 + i) * 12;
    float v[12];
    float m = -3.0e38f;
    for (int k = 0; k < 12; ++k) { v[k] = a[k] / norm; m = fmaxf(m, v[k]); }
    float ssum = 0.f;
    for (int k = 0; k < 12; ++k) { v[k] = expf(v[k] - m); ssum += v[k]; }
    float inv = 1.0f / ssum;
    for (int k = 0; k < 12; ++k) sw[e * 12 + k] = v[k] * inv;
}

// ---------------- build combined 9x9 weights: Wc[e][o][c][81] --------------
__global__ void build_w(const float* __restrict__ w3, const float* __restrict__ w5,
                        const float* __restrict__ w7, const float* __restrict__ w1,
                        const float* __restrict__ s3dw, const float* __restrict__ s3pw,
                        const float* __restrict__ s5dw, const float* __restrict__ s5pw,
                        const float* __restrict__ d3, const float* __restrict__ d5,
                        const float* __restrict__ sw, float* __restrict__ Wc) {
    int gid = blockIdx.x * 256 + threadIdx.x;  // 10*64*64*81 = 3,317,760
    int tap = gid % TAPS;
    int rc  = gid / TAPS;
    int c = rc & 63;
    int ro = rc >> 6;
    int o = ro & 63;
    int e = ro >> 6;
    int dy = tap / KW - KR, dx = tap % KW - KR;
    const float* w = sw + e * 12;
    int eoc = (e * 64 + o) * 64 + c;
    int ec  = e * 64 + c;
    float val = 0.f;
    int ady = dy < 0 ? -dy : dy, adx = dx < 0 ? -dx : dx;
    if (ady <= 1 && adx <= 1) {
        val += w[1] * w3[eoc * 9 + (dy + 1) * 3 + (dx + 1)];
        val += w[7] * s3pw[eoc] * s3dw[ec * 9 + (dy + 1) * 3 + (dx + 1)];
    }
    if (ady <= 2 && adx <= 2) {
        val += w[2] * w5[eoc * 25 + (dy + 2) * 5 + (dx + 2)];
        val += w[8] * s5pw[eoc] * s5dw[ec * 25 + (dy + 2) * 5 + (dx + 2)];
        if (((dy | dx) & 1) == 0)
            val += w[9] * d3[eoc * 9 + (dy / 2 + 1) * 3 + (dx / 2 + 1)];
    }
    if (ady <= 3 && adx <= 3)
        val += w[3] * w7[eoc * 49 + (dy + 3) * 7 + (dx + 3)];
    if (((dy | dx) & 1) == 0)
        val += w[10] * d5[eoc * 25 + (dy / 2 + 2) * 5 + (dx / 2 + 2)];
    if (dy == 0 && dx == 0) {
        val += w[4] * w1[eoc];
        if (o == c) val += w[0];
    }
    Wc[gid] = val;
}

// ---------------- pools (also zero-inits acc) ------------------------------
__global__ void pool_node(const float* __restrict__ s0, const float* __restrict__ s1,
                          const float* __restrict__ s2, const float* __restrict__ s3,
                          float* __restrict__ acc, const float* __restrict__ sw,
                          int ebase, int nedges) {
    int gid = blockIdx.x * 256 + threadIdx.x;  // over 64*256*1024
    int x = gid & 31;
    int y = (gid >> 5) & 31;
    int plane = gid >> 10;
    const float* states[4] = {s0, s1, s2, s3};
    float val = 0.f;
    for (int i = 0; i < nedges; ++i) {
        const float* base = states[i] + (plane << 10);
        float mx = -3.0e38f;
        float sum = 0.f;
        #pragma unroll
        for (int dy = -1; dy <= 1; ++dy) {
            #pragma unroll
            for (int dx = -1; dx <= 1; ++dx) {
                int yy = y + dy, xx = x + dx;
                if ((unsigned)yy < 32u && (unsigned)xx < 32u) {
                    float v = base[yy * 32 + xx];
                    mx = fmaxf(mx, v);
                    sum += v;
                }
            }
        }
        val += sw[(ebase + i) * 12 + 5] * mx + sw[(ebase + i) * 12 + 6] * (sum * (1.0f / 9.0f));
    }
    acc[gid] = val;
}

// ---------------- combined 9x9 conv for one edge (v2) ----------------------
// Block: 256 threads = (4 xh) x (32 y) x (2 og). Each thread: 8 x-outputs,
// 1 y-row, 2 output channels. Block covers 4 o-planes of one batch image.
// Grid: 64 n x 16 oQuad = 1024 blocks.
#define TILE 40
__global__ __launch_bounds__(256) void conv_edge(const float* __restrict__ s,
                                                 float* __restrict__ acc,
                                                 const float* __restrict__ Wc,
                                                 const int* __restrict__ idx,
                                                 int e) {
    __shared__ float tile[TILE * TILE];
    __shared__ int ids[PC];
    int t = threadIdx.x;
    int oQuad = blockIdx.x & 15;
    int n = blockIdx.x >> 4;
    if (t < PC) ids[t] = idx[e * PC + t];
    // zero border ONCE (interior overwritten each channel; border stays 0)
    for (int l = t; l < TILE * TILE; l += 256) {
        int ty = l / TILE, tx = l - ty * TILE;
        if (ty < KR || ty >= 36 || tx < KR || tx >= 36) tile[l] = 0.f;
    }
    // compute mapping
    int ogu = __builtin_amdgcn_readfirstlane(t >> 7);  // wave-uniform (waves 0,1 -> 0; 2,3 -> 1)
    int xh = t & 3;
    int y  = (t >> 2) & 31;
    int x0 = xh * 8;
    // staging mapping: one float4 per thread covers the 32x32 interior
    int sty = KR + (t >> 3);          // rows 4..35
    int stx = t & 7;                  // col groups
    float* twr = &tile[sty * TILE + KR + stx * 4];
    const float* sgrd_off = 0;  (void)sgrd_off;

    f2v a2[2][8];
    #pragma unroll
    for (int k = 0; k < 2; ++k)
        #pragma unroll
        for (int x = 0; x < 8; ++x) a2[k][x] = (f2v){0.f, 0.f};

    // uniform weight bases (scalar loads)
    const float* wb0 = Wc + (size_t)((e * 64 + oQuad * 4 + 2 * ogu + 0) * 64) * TAPS;
    const float* wb1 = Wc + (size_t)((e * 64 + oQuad * 4 + 2 * ogu + 1) * 64) * TAPS;

    __syncthreads();  // ids + border zeros visible

    for (int c = 0; c < PC; ++c) {
        const float* sp = s + ((size_t)(n * CF + ids[c]) << 10);
        f4v v = *(const f4v*)(sp + ((sty - KR) << 5) + stx * 4);
        __syncthreads();          // previous iteration's readers done
        *(f4v*)twr = v;
        __syncthreads();          // tile ready

        const float* wr0 = wb0 + c * TAPS;
        const float* wr1 = wb1 + c * TAPS;

        for (int dy = 0; dy < KW; ++dy) {
            const f4v* rowt = (const f4v*)&tile[(y + dy) * TILE];
            f4v i0 = rowt[2 * xh + 0];
            f4v i1 = rowt[2 * xh + 1];
            f4v i2 = rowt[2 * xh + 2];
            f4v i3 = rowt[2 * xh + 3];
            f2v iv[8];
            iv[0] = __builtin_shufflevector(i0, i0, 0, 1);
            iv[1] = __builtin_shufflevector(i0, i0, 2, 3);
            iv[2] = __builtin_shufflevector(i1, i1, 0, 1);
            iv[3] = __builtin_shufflevector(i1, i1, 2, 3);
            iv[4] = __builtin_shufflevector(i2, i2, 0, 1);
            iv[5] = __builtin_shufflevector(i2, i2, 2, 3);
            iv[6] = __builtin_shufflevector(i3, i3, 0, 1);
            iv[7] = __builtin_shufflevector(i3, i3, 2, 3);
            #pragma unroll
            for (int k = 0; k < 2; ++k) {
                const float* wr = (k == 0 ? wr0 : wr1) + dy * KW;
                float w0s = wr[0], w1s = wr[1], w2s = wr[2], w3s = wr[3], w4s = wr[4];
                float w5s = wr[5], w6s = wr[6], w7s = wr[7], w8s = wr[8];
                f2v eA = (f2v){w0s, w1s}, eB = (f2v){w2s, w3s};
                f2v eC = (f2v){w4s, w5s}, eD = (f2v){w6s, w7s};
                f2v oA = (f2v){w1s, w2s}, oB = (f2v){w3s, w4s};
                f2v oC = (f2v){w5s, w6s}, oD = (f2v){w7s, w8s};
                #pragma unroll
                for (int m = 0; m < 4; ++m) {
                    // even x = 2m: dx pairs (0,1)(2,3)(4,5)(6,7) + tail dx=8
                    a2[k][2 * m] = __builtin_elementwise_fma(eA, iv[m],     a2[k][2 * m]);
                    a2[k][2 * m] = __builtin_elementwise_fma(eB, iv[m + 1], a2[k][2 * m]);
                    a2[k][2 * m] = __builtin_elementwise_fma(eC, iv[m + 2], a2[k][2 * m]);
                    a2[k][2 * m] = __builtin_elementwise_fma(eD, iv[m + 3], a2[k][2 * m]);
                    a2[k][2 * m].x = fmaf(w8s, iv[m + 4].x, a2[k][2 * m].x);
                    // odd x = 2m+1: dx pairs (1,2)(3,4)(5,6)(7,8) + tail dx=0
                    a2[k][2 * m + 1] = __builtin_elementwise_fma(oA, iv[m + 1], a2[k][2 * m + 1]);
                    a2[k][2 * m + 1] = __builtin_elementwise_fma(oB, iv[m + 2], a2[k][2 * m + 1]);
                    a2[k][2 * m + 1] = __builtin_elementwise_fma(oC, iv[m + 3], a2[k][2 * m + 1]);
                    a2[k][2 * m + 1] = __builtin_elementwise_fma(oD, iv[m + 4], a2[k][2 * m + 1]);
                    a2[k][2 * m + 1].x = fmaf(w0s, iv[m].y, a2[k][2 * m + 1].x);
                }
            }
        }
    }

    // epilogue: horizontal add + RMW into acc at gathered output channels
    #pragma unroll
    for (int k = 0; k < 2; ++k) {
        int oIdx = ids[oQuad * 4 + 2 * ogu + k];
        float* op = acc + ((size_t)(n * CF + oIdx) << 10) + y * HW + x0;
        #pragma unroll
        for (int x = 0; x < 8; ++x)
            op[x] += a2[k][x].x + a2[k][x].y;
    }
}

extern "C" void kernel_launch(void* const* d_in, const int* in_sizes, int n_in,
                              void* d_out, int out_size, void* d_ws, size_t ws_size,
                              hipStream_t stream) {
    const float* x    = (const float*)d_in[0];
    const float* arch = (const float*)d_in[1];
    const float* norms= (const float*)d_in[2];
    const int*   idx  = (const int*)d_in[3];
    const float* w3   = (const float*)d_in[4];
    const float* w5   = (const float*)d_in[5];
    const float* w7   = (const float*)d_in[6];
    const float* w1   = (const float*)d_in[7];
    const float* s3dw = (const float*)d_in[8];
    const float* s3pw = (const float*)d_in[9];
    const float* s5dw = (const float*)d_in[10];
    const float* s5pw = (const float*)d_in[11];
    const float* d3   = (const float*)d_in[12];
    const float* d5   = (const float*)d_in[13];
    float* out = (float*)d_out;

    const size_t S = (size_t)NB * CF * HW * HW;  // 16,777,216 floats
    float* st1 = (float*)d_ws;
    float* st2 = st1 + S;
    float* st3 = st2 + S;
    float* Wc  = st3 + S;                         // 10*64*64*81 floats
    float* sw  = Wc + (size_t)NEDGE * 64 * 64 * TAPS;

    softmax_kernel<<<1, 64, 0, stream>>>(arch, norms, sw);
    build_w<<<(NEDGE * 64 * 64 * TAPS) / 256, 256, 0, stream>>>(
        w3, w5, w7, w1, s3dw, s3pw, s5dw, s5pw, d3, d5, sw, Wc);

    float* states[5] = {(float*)x, st1, st2, st3, out};
    int e = 0;
    for (int node = 0; node < 4; ++node) {
        int ebase = node * (node + 1) / 2;
        pool_node<<<(int)(S / 256), 256, 0, stream>>>(
            states[0], states[1], states[2], states[3],
            states[node + 1], sw, ebase, node + 1);
        for (int i = 0; i <= node; ++i) {
            conv_edge<<<NB * 16, 256, 0, stream>>>(states[i], states[node + 1], Wc, idx, e);
            ++e;
        }
    }
}

// Round 3
// 5054.998 us; speedup vs baseline: 2.0445x; 1.0288x over previous
//
#include <hip/hip_runtime.h>
#include <hip/hip_bf16.h>
#include <math.h>

// LPCDARTS forward on MI355X — v3.
// One dense 9x9 conv per edge (combined weights Wc[e][o][c][81]).
// v3: LDS stride 44 (bank-conflict-free b128), 4-row register ring
// (4y x 4x x 2o outputs per thread), SGPR weights, packed-fp32 FMA,
// prefetched global->LDS staging.

#define NB 64      // batch
#define CF 256     // full channels
#define PC 64      // gathered channels
#define HW 32
#define NEDGE 10
#define KR 4       // conv radius (9x9)
#define KW 9
#define TAPS 81

#define TROWS 40
#define TSTRIDE 44   // 44 mod 32 = 12 -> uniform bank spread for b128

typedef float f4v __attribute__((ext_vector_type(4)));
typedef float f2v __attribute__((ext_vector_type(2)));

// ---------------- softmax over arch params (10 edges x 12 ops) -------------
__global__ void softmax_kernel(const float* __restrict__ arch,
                               const float* __restrict__ norms,
                               float* __restrict__ sw) {
    int e = threadIdx.x;
    if (e >= NEDGE) return;
    int node = 0, i = e;
    while (i > node) { i -= node + 1; node++; }
    float norm = fmaxf(norms[node * 5 + i], 1e-5f);
    const float* a = arch + (node * 5 + i) * 12;
    float v[12];
    float m = -3.0e38f;
    for (int k = 0; k < 12; ++k) { v[k] = a[k] / norm; m = fmaxf(m, v[k]); }
    float ssum = 0.f;
    for (int k = 0; k < 12; ++k) { v[k] = expf(v[k] - m); ssum += v[k]; }
    float inv = 1.0f / ssum;
    for (int k = 0; k < 12; ++k) sw[e * 12 + k] = v[k] * inv;
}

// ---------------- build combined 9x9 weights: Wc[e][o][c][81] --------------
__global__ void build_w(const float* __restrict__ w3, const float* __restrict__ w5,
                        const float* __restrict__ w7, const float* __restrict__ w1,
                        const float* __restrict__ s3dw, const float* __restrict__ s3pw,
                        const float* __restrict__ s5dw, const float* __restrict__ s5pw,
                        const float* __restrict__ d3, const float* __restrict__ d5,
                        const float* __restrict__ sw, float* __restrict__ Wc) {
    int gid = blockIdx.x * 256 + threadIdx.x;  // 10*64*64*81 = 3,317,760
    int tap = gid % TAPS;
    int rc  = gid / TAPS;
    int c = rc & 63;
    int ro = rc >> 6;
    int o = ro & 63;
    int e = ro >> 6;
    int dy = tap / KW - KR, dx = tap % KW - KR;
    const float* w = sw + e * 12;
    int eoc = (e * 64 + o) * 64 + c;
    int ec  = e * 64 + c;
    float val = 0.f;
    int ady = dy < 0 ? -dy : dy, adx = dx < 0 ? -dx : dx;
    if (ady <= 1 && adx <= 1) {
        val += w[1] * w3[eoc * 9 + (dy + 1) * 3 + (dx + 1)];
        val += w[7] * s3pw[eoc] * s3dw[ec * 9 + (dy + 1) * 3 + (dx + 1)];
    }
    if (ady <= 2 && adx <= 2) {
        val += w[2] * w5[eoc * 25 + (dy + 2) * 5 + (dx + 2)];
        val += w[8] * s5pw[eoc] * s5dw[ec * 25 + (dy + 2) * 5 + (dx + 2)];
        if (((dy | dx) & 1) == 0)
            val += w[9] * d3[eoc * 9 + (dy / 2 + 1) * 3 + (dx / 2 + 1)];
    }
    if (ady <= 3 && adx <= 3)
        val += w[3] * w7[eoc * 49 + (dy + 3) * 7 + (dx + 3)];
    if (((dy | dx) & 1) == 0)
        val += w[10] * d5[eoc * 25 + (dy / 2 + 2) * 5 + (dx / 2 + 2)];
    if (dy == 0 && dx == 0) {
        val += w[4] * w1[eoc];
        if (o == c) val += w[0];
    }
    Wc[gid] = val;
}

// ---------------- pools (also zero-inits acc) ------------------------------
__global__ void pool_node(const float* __restrict__ s0, const float* __restrict__ s1,
                          const float* __restrict__ s2, const float* __restrict__ s3,
                          float* __restrict__ acc, const float* __restrict__ sw,
                          int ebase, int nedges) {
    int gid = blockIdx.x * 256 + threadIdx.x;  // over 64*256*1024
    int x = gid & 31;
    int y = (gid >> 5) & 31;
    int plane = gid >> 10;
    const float* states[4] = {s0, s1, s2, s3};
    float val = 0.f;
    for (int i = 0; i < nedges; ++i) {
        const float* base = states[i] + (plane << 10);
        float mx = -3.0e38f;
        float sum = 0.f;
        #pragma unroll
        for (int dy = -1; dy <= 1; ++dy) {
            #pragma unroll
            for (int dx = -1; dx <= 1; ++dx) {
                int yy = y + dy, xx = x + dx;
                if ((unsigned)yy < 32u && (unsigned)xx < 32u) {
                    float v = base[yy * 32 + xx];
                    mx = fmaxf(mx, v);
                    sum += v;
                }
            }
        }
        val += sw[(ebase + i) * 12 + 5] * mx + sw[(ebase + i) * 12 + 6] * (sum * (1.0f / 9.0f));
    }
    acc[gid] = val;
}

// ---------------- combined 9x9 conv for one edge (v3) ----------------------
// Block: 256 threads = 4 waves. Wave w = o-pair; lanes = 8 xh x 8 yq.
// Thread: 4x x 4y x 2o outputs. Block covers 8 o-planes of one image.
// Grid: 64 n x 8 og = 512 blocks.
__global__ __launch_bounds__(256, 2) void conv_edge(const float* __restrict__ s,
                                                    float* __restrict__ acc,
                                                    const float* __restrict__ Wc,
                                                    const int* __restrict__ idx,
                                                    int e) {
    __shared__ float tile[TROWS * TSTRIDE];
    __shared__ int ids[PC];
    int t = threadIdx.x;
    int og = blockIdx.x & 7;
    int n = blockIdx.x >> 3;
    if (t < PC) ids[t] = idx[e * PC + t];
    // zero border ONCE (interior rewritten each channel; border stays 0)
    for (int l = t; l < TROWS * TSTRIDE; l += 256) {
        int ty = l / TSTRIDE, tx = l - ty * TSTRIDE;
        if (ty < KR || ty >= 36 || tx < KR || tx >= 36) tile[l] = 0.f;
    }

    int op = __builtin_amdgcn_readfirstlane(t >> 6);   // wave index = o-pair
    int lane = t & 63;
    int xh = lane & 7;          // x block: outputs 4*xh .. 4*xh+3
    int yq = (lane >> 3) & 7;   // y block: outputs 4*yq .. 4*yq+3
    int x0 = xh * 4;
    int yb = yq * 4;

    // staging mapping: one float4 per thread covers the 32x32 interior
    int srow = t >> 3;                 // 0..31
    int stx = t & 7;                   // 0..7
    float* twr = &tile[(KR + srow) * TSTRIDE + KR + stx * 4];
    const float* sgbase = 0; (void)sgbase;

    // accumulators: [o-in-pair][y][x], each f2v is dot-product halves
    f2v a[2][4][4];
    #pragma unroll
    for (int k = 0; k < 2; ++k)
        #pragma unroll
        for (int j = 0; j < 4; ++j)
            #pragma unroll
            for (int x = 0; x < 4; ++x) a[k][j][x] = (f2v){0.f, 0.f};

    int o0 = og * 8 + op * 2;
    const float* wb0 = Wc + (size_t)((e * 64 + o0 + 0) * 64) * TAPS;
    const float* wb1 = Wc + (size_t)((e * 64 + o0 + 1) * 64) * TAPS;

    __syncthreads();  // ids + border zeros visible

    // prefetch channel 0
    f4v v = *(const f4v*)(s + ((size_t)(n * CF + ids[0]) << 10) + (srow << 5) + stx * 4);

    for (int c = 0; c < PC; ++c) {
        __syncthreads();          // previous iteration's readers done
        *(f4v*)twr = v;
        __syncthreads();          // tile ready
        if (c + 1 < PC)           // prefetch next channel during compute
            v = *(const f4v*)(s + ((size_t)(n * CF + ids[c + 1]) << 10) + (srow << 5) + stx * 4);

        const float* wr0 = wb0 + c * TAPS;
        const float* wr1 = wb1 + c * TAPS;

        // register ring of 4 input rows, 3 f4v each (12 floats: cols x0..x0+11)
        f4v r[4][3];
        #pragma unroll
        for (int j = 0; j < 4; ++j) {
            const f4v* rp = (const f4v*)&tile[(yb + j) * TSTRIDE + x0];
            r[j][0] = rp[0]; r[j][1] = rp[1]; r[j][2] = rp[2];
        }

        #pragma unroll
        for (int dy = 0; dy < KW; ++dy) {
            #pragma unroll
            for (int j = 0; j < 4; ++j) {
                const f4v* rr = r[(dy + j) & 3];
                f2v iv[6];
                iv[0] = __builtin_shufflevector(rr[0], rr[0], 0, 1);
                iv[1] = __builtin_shufflevector(rr[0], rr[0], 2, 3);
                iv[2] = __builtin_shufflevector(rr[1], rr[1], 0, 1);
                iv[3] = __builtin_shufflevector(rr[1], rr[1], 2, 3);
                iv[4] = __builtin_shufflevector(rr[2], rr[2], 0, 1);
                iv[5] = __builtin_shufflevector(rr[2], rr[2], 2, 3);
                #pragma unroll
                for (int k = 0; k < 2; ++k) {
                    const float* wr = (k == 0 ? wr0 : wr1) + dy * KW;
                    float w0s = wr[0], w1s = wr[1], w2s = wr[2], w3s = wr[3], w4s = wr[4];
                    float w5s = wr[5], w6s = wr[6], w7s = wr[7], w8s = wr[8];
                    f2v eA = (f2v){w0s, w1s}, eB = (f2v){w2s, w3s};
                    f2v eC = (f2v){w4s, w5s}, eD = (f2v){w6s, w7s};
                    f2v oA = (f2v){w1s, w2s}, oB = (f2v){w3s, w4s};
                    f2v oC = (f2v){w5s, w6s}, oD = (f2v){w7s, w8s};
                    #pragma unroll
                    for (int m = 0; m < 2; ++m) {
                        // even local x = 2m
                        a[k][j][2 * m] = __builtin_elementwise_fma(eA, iv[m],     a[k][j][2 * m]);
                        a[k][j][2 * m] = __builtin_elementwise_fma(eB, iv[m + 1], a[k][j][2 * m]);
                        a[k][j][2 * m] = __builtin_elementwise_fma(eC, iv[m + 2], a[k][j][2 * m]);
                        a[k][j][2 * m] = __builtin_elementwise_fma(eD, iv[m + 3], a[k][j][2 * m]);
                        a[k][j][2 * m].x = fmaf(w8s, iv[m + 4].x, a[k][j][2 * m].x);
                        // odd local x = 2m+1
                        a[k][j][2 * m + 1] = __builtin_elementwise_fma(oA, iv[m + 1], a[k][j][2 * m + 1]);
                        a[k][j][2 * m + 1] = __builtin_elementwise_fma(oB, iv[m + 2], a[k][j][2 * m + 1]);
                        a[k][j][2 * m + 1] = __builtin_elementwise_fma(oC, iv[m + 3], a[k][j][2 * m + 1]);
                        a[k][j][2 * m + 1] = __builtin_elementwise_fma(oD, iv[m + 4], a[k][j][2 * m + 1]);
                        a[k][j][2 * m + 1].x = fmaf(w0s, iv[m].y, a[k][j][2 * m + 1].x);
                    }
                }
            }
            // slide: load row (yb + dy + 4) into the slot just vacated
            if (dy < 8) {
                const f4v* rp = (const f4v*)&tile[(yb + dy + 4) * TSTRIDE + x0];
                f4v* rn = r[dy & 3];
                rn[0] = rp[0]; rn[1] = rp[1]; rn[2] = rp[2];
            }
        }
    }

    // epilogue: horizontal add + vector RMW into acc at gathered channels
    #pragma unroll
    for (int k = 0; k < 2; ++k) {
        int oIdx = ids[o0 + k];
        #pragma unroll
        for (int j = 0; j < 4; ++j) {
            float* op_ = acc + ((size_t)(n * CF + oIdx) << 10) + (yb + j) * HW + x0;
            f4v cur = *(f4v*)op_;
            cur.x += a[k][j][0].x + a[k][j][0].y;
            cur.y += a[k][j][1].x + a[k][j][1].y;
            cur.z += a[k][j][2].x + a[k][j][2].y;
            cur.w += a[k][j][3].x + a[k][j][3].y;
            *(f4v*)op_ = cur;
        }
    }
}

extern "C" void kernel_launch(void* const* d_in, const int* in_sizes, int n_in,
                              void* d_out, int out_size, void* d_ws, size_t ws_size,
                              hipStream_t stream) {
    const float* x    = (const float*)d_in[0];
    const float* arch = (const float*)d_in[1];
    const float* norms= (const float*)d_in[2];
    const int*   idx  = (const int*)d_in[3];
    const float* w3   = (const float*)d_in[4];
    const float* w5   = (const float*)d_in[5];
    const float* w7   = (const float*)d_in[6];
    const float* w1   = (const float*)d_in[7];
    const float* s3dw = (const float*)d_in[8];
    const float* s3pw = (const float*)d_in[9];
    const float* s5dw = (const float*)d_in[10];
    const float* s5pw = (const float*)d_in[11];
    const float* d3   = (const float*)d_in[12];
    const float* d5   = (const float*)d_in[13];
    float* out = (float*)d_out;

    const size_t S = (size_t)NB * CF * HW * HW;  // 16,777,216 floats
    float* st1 = (float*)d_ws;
    float* st2 = st1 + S;
    float* st3 = st2 + S;
    float* Wc  = st3 + S;                         // 10*64*64*81 floats
    float* sw  = Wc + (size_t)NEDGE * 64 * 64 * TAPS;

    softmax_kernel<<<1, 64, 0, stream>>>(arch, norms, sw);
    build_w<<<(NEDGE * 64 * 64 * TAPS) / 256, 256, 0, stream>>>(
        w3, w5, w7, w1, s3dw, s3pw, s5dw, s5pw, d3, d5, sw, Wc);

    float* states[5] = {(float*)x, st1, st2, st3, out};
    int e = 0;
    for (int node = 0; node < 4; ++node) {
        int ebase = node * (node + 1) / 2;
        pool_node<<<(int)(S / 256), 256, 0, stream>>>(
            states[0], states[1], states[2], states[3],
            states[node + 1], sw, ebase, node + 1);
        for (int i = 0; i <= node; ++i) {
            conv_edge<<<NB * 8, 256, 0, stream>>>(states[i], states[node + 1], Wc, idx, e);
            ++e;
        }
    }
}

// Round 4
// 4854.516 us; speedup vs baseline: 2.1290x; 1.0413x over previous
//
#include <hip/hip_runtime.h>
#include <hip/hip_bf16.h>
#include <math.h>

// LPCDARTS forward on MI355X — v4.
// One dense 9x9 conv per edge (combined weights). v4 key idea: pack the
// fp32 math along the CHANNEL dim (2 channels per f2v) so every FMA is a
// v_pk_fma_f32 with an aligned SGPR weight pair and an aligned VGPR input
// pair — no shuffles, no tails. LDS tile holds 2 interleaved channels.

#define NB 64
#define CF 256
#define PC 64
#define HW 32
#define NEDGE 10
#define KR 4
#define KW 9
#define TAPS 81

#define TSX 42            // tile stride in float2 units (40 + 2 pad)
#define TROWS 40

typedef float f4v __attribute__((ext_vector_type(4)));
typedef float f2v __attribute__((ext_vector_type(2)));

__device__ __forceinline__ f2v getcol(const f4v (&r)[8], int c) {
    f4v v = r[c >> 1];
    return (c & 1) ? (f2v){v.z, v.w} : (f2v){v.x, v.y};
}

// ---------------- softmax over arch params (10 edges x 12 ops) -------------
__global__ void softmax_kernel(const float* __restrict__ arch,
                               const float* __restrict__ norms,
                               float* __restrict__ sw) {
    int e = threadIdx.x;
    if (e >= NEDGE) return;
    int node = 0, i = e;
    while (i > node) { i -= node + 1; node++; }
    float norm = fmaxf(norms[node * 5 + i], 1e-5f);
    const float* a = arch + (node * 5 + i) * 12;
    float v[12];
    float m = -3.0e38f;
    for (int k = 0; k < 12; ++k) { v[k] = a[k] / norm; m = fmaxf(m, v[k]); }
    float ssum = 0.f;
    for (int k = 0; k < 12; ++k) { v[k] = expf(v[k] - m); ssum += v[k]; }
    float inv = 1.0f / ssum;
    for (int k = 0; k < 12; ++k) sw[e * 12 + k] = v[k] * inv;
}

// ---------------- build combined 9x9 weights -------------------------------
// NEW layout: Wc[e][o][g][tap][2] where g = c>>1, last dim = c&1 (c-pairs
// innermost -> aligned SGPR pairs for v_pk_fma_f32).
__global__ void build_w(const float* __restrict__ w3, const float* __restrict__ w5,
                        const float* __restrict__ w7, const float* __restrict__ w1,
                        const float* __restrict__ s3dw, const float* __restrict__ s3pw,
                        const float* __restrict__ s5dw, const float* __restrict__ s5pw,
                        const float* __restrict__ d3, const float* __restrict__ d5,
                        const float* __restrict__ sw, float* __restrict__ Wc) {
    int gid = blockIdx.x * 256 + threadIdx.x;  // 10*64*64*81 = 3,317,760
    int tap = gid % TAPS;
    int rc  = gid / TAPS;
    int c = rc & 63;
    int ro = rc >> 6;
    int o = ro & 63;
    int e = ro >> 6;
    int dy = tap / KW - KR, dx = tap % KW - KR;
    const float* w = sw + e * 12;
    int eoc = (e * 64 + o) * 64 + c;
    int ec  = e * 64 + c;
    float val = 0.f;
    int ady = dy < 0 ? -dy : dy, adx = dx < 0 ? -dx : dx;
    if (ady <= 1 && adx <= 1) {
        val += w[1] * w3[eoc * 9 + (dy + 1) * 3 + (dx + 1)];
        val += w[7] * s3pw[eoc] * s3dw[ec * 9 + (dy + 1) * 3 + (dx + 1)];
    }
    if (ady <= 2 && adx <= 2) {
        val += w[2] * w5[eoc * 25 + (dy + 2) * 5 + (dx + 2)];
        val += w[8] * s5pw[eoc] * s5dw[ec * 25 + (dy + 2) * 5 + (dx + 2)];
        if (((dy | dx) & 1) == 0)
            val += w[9] * d3[eoc * 9 + (dy / 2 + 1) * 3 + (dx / 2 + 1)];
    }
    if (ady <= 3 && adx <= 3)
        val += w[3] * w7[eoc * 49 + (dy + 3) * 7 + (dx + 3)];
    if (((dy | dx) & 1) == 0)
        val += w[10] * d5[eoc * 25 + (dy / 2 + 2) * 5 + (dx / 2 + 2)];
    if (dy == 0 && dx == 0) {
        val += w[4] * w1[eoc];
        if (o == c) val += w[0];
    }
    // packed layout store
    int g = c >> 1, c2 = c & 1;
    Wc[((((size_t)(e * 64 + o) * 32 + g) * TAPS) + tap) * 2 + c2] = val;
}

// ---------------- pools (also zero-inits acc) ------------------------------
__global__ void pool_node(const float* __restrict__ s0, const float* __restrict__ s1,
                          const float* __restrict__ s2, const float* __restrict__ s3,
                          float* __restrict__ acc, const float* __restrict__ sw,
                          int ebase, int nedges) {
    int gid = blockIdx.x * 256 + threadIdx.x;  // over 64*256*1024
    int x = gid & 31;
    int y = (gid >> 5) & 31;
    int plane = gid >> 10;
    const float* states[4] = {s0, s1, s2, s3};
    float val = 0.f;
    for (int i = 0; i < nedges; ++i) {
        const float* base = states[i] + (plane << 10);
        float mx = -3.0e38f;
        float sum = 0.f;
        #pragma unroll
        for (int dy = -1; dy <= 1; ++dy) {
            #pragma unroll
            for (int dx = -1; dx <= 1; ++dx) {
                int yy = y + dy, xx = x + dx;
                if ((unsigned)yy < 32u && (unsigned)xx < 32u) {
                    float v = base[yy * 32 + xx];
                    mx = fmaxf(mx, v);
                    sum += v;
                }
            }
        }
        val += sw[(ebase + i) * 12 + 5] * mx + sw[(ebase + i) * 12 + 6] * (sum * (1.0f / 9.0f));
    }
    acc[gid] = val;
}

// ---------------- combined 9x9 conv for one edge (v4) ----------------------
// Block: 256 thr = 4 waves; wave = o-pair (o wave-uniform -> SGPR weights).
// Lane: 4 xh x 16 yg. Thread outputs: 8x x 2y x 2o. 2 channels per K-iter,
// interleaved float2 LDS tile. Grid: 64 n x 8 og = 512 blocks.
__global__ __launch_bounds__(256, 2) void conv_edge(const float* __restrict__ s,
                                                    float* __restrict__ acc,
                                                    const float* __restrict__ Wc,
                                                    const int* __restrict__ idx,
                                                    int e) {
    __shared__ f2v tile[TROWS * TSX];
    int t = threadIdx.x;
    int og = blockIdx.x & 7;
    int n = blockIdx.x >> 3;

    // zero whole tile once (interior rewritten each iter; border stays 0)
    for (int l = t; l < TROWS * TSX; l += 256) tile[l] = (f2v){0.f, 0.f};

    int wave = __builtin_amdgcn_readfirstlane(t >> 6);
    int lane = t & 63;
    int xh = lane & 3;            // x0 = 8*xh
    int yg = lane >> 2;           // y0 = 2*yg
    int x0 = xh * 8, y0 = yg * 2;

    // staging map: thread covers 4 pixels (row srow, cols 4sxq..4sxq+3), both ch
    int srow = t >> 3, sxq = t & 7;
    int wr_r = KR + srow;
    f2v* twr = &tile[wr_r * TSX + ((wr_r >> 3) & 1) * 2 + KR + 4 * sxq];
    int goff = (srow << 5) + 4 * sxq;

    f2v a[2][2][8];               // [o][y][x]
    #pragma unroll
    for (int k = 0; k < 2; ++k)
        #pragma unroll
        for (int j = 0; j < 2; ++j)
            #pragma unroll
            for (int x = 0; x < 8; ++x) a[k][j][x] = (f2v){0.f, 0.f};

    int o0 = og * 8 + wave * 2;
    const float* wbase0 = Wc + (size_t)(e * 64 + o0) * 32 * (TAPS * 2);
    const float* wbase1 = wbase0 + 32 * (TAPS * 2);

    // prefetch channel pair 0
    int idA = idx[e * PC + 0], idB = idx[e * PC + 1];
    f4v p0 = *(const f4v*)(s + (((size_t)n * CF + idA) << 10) + goff);
    f4v p1 = *(const f4v*)(s + (((size_t)n * CF + idB) << 10) + goff);

    for (int g = 0; g < 32; ++g) {
        __syncthreads();          // previous iteration's readers done (+tile zeros)
        f4v wv0 = {p0.x, p1.x, p0.y, p1.y};
        f4v wv1 = {p0.z, p1.z, p0.w, p1.w};
        ((f4v*)twr)[0] = wv0;
        ((f4v*)twr)[1] = wv1;
        __syncthreads();          // tile ready
        if (g + 1 < 32) {         // prefetch next channel pair during compute
            int iA = idx[e * PC + 2 * g + 2], iB = idx[e * PC + 2 * g + 3];
            p0 = *(const f4v*)(s + (((size_t)n * CF + iA) << 10) + goff);
            p1 = *(const f4v*)(s + (((size_t)n * CF + iB) << 10) + goff);
        }

        const float* wp0 = wbase0 + g * (TAPS * 2);
        const float* wp1 = wbase1 + g * (TAPS * 2);

        // 2-row register ring; rows are 8 aligned f4v (16 f2 cols x0..x0+15)
        f4v ring[2][8];
        {
            int r = y0;
            const f2v* rp = &tile[r * TSX + ((r >> 3) & 1) * 2 + x0];
            #pragma unroll
            for (int k = 0; k < 8; ++k) ring[0][k] = ((const f4v*)rp)[k];
            r = y0 + 1;
            rp = &tile[r * TSX + ((r >> 3) & 1) * 2 + x0];
            #pragma unroll
            for (int k = 0; k < 8; ++k) ring[1][k] = ((const f4v*)rp)[k];
        }

        #pragma unroll
        for (int dy = 0; dy < KW; ++dy) {
            #pragma unroll
            for (int dx = 0; dx < KW; ++dx) {
                f2v w0 = *(const f2v*)&wp0[(dy * KW + dx) * 2];  // uniform -> s_load pair
                f2v w1 = *(const f2v*)&wp1[(dy * KW + dx) * 2];
                #pragma unroll
                for (int x = 0; x < 8; ++x) {
                    f2v iA = getcol(ring[dy & 1], x + dx);        // row y0+dy
                    f2v iB = getcol(ring[(dy + 1) & 1], x + dx);  // row y0+dy+1
                    a[0][0][x] = __builtin_elementwise_fma(w0, iA, a[0][0][x]);
                    a[0][1][x] = __builtin_elementwise_fma(w0, iB, a[0][1][x]);
                    a[1][0][x] = __builtin_elementwise_fma(w1, iA, a[1][0][x]);
                    a[1][1][x] = __builtin_elementwise_fma(w1, iB, a[1][1][x]);
                }
            }
            if (dy < KW - 1) {    // slide: replace row y0+dy with row y0+dy+2
                int r = y0 + dy + 2;
                const f2v* rp = &tile[r * TSX + ((r >> 3) & 1) * 2 + x0];
                #pragma unroll
                for (int k = 0; k < 8; ++k) ring[dy & 1][k] = ((const f4v*)rp)[k];
            }
        }
    }

    // epilogue: horizontal add over the channel pair + RMW into acc
    #pragma unroll
    for (int k = 0; k < 2; ++k) {
        int oIdx = idx[e * PC + o0 + k];
        #pragma unroll
        for (int j = 0; j < 2; ++j) {
            float* op = acc + (((size_t)n * CF + oIdx) << 10) + (y0 + j) * HW + x0;
            f4v c0 = ((f4v*)op)[0], c1 = ((f4v*)op)[1];
            c0.x += a[k][j][0].x + a[k][j][0].y;
            c0.y += a[k][j][1].x + a[k][j][1].y;
            c0.z += a[k][j][2].x + a[k][j][2].y;
            c0.w += a[k][j][3].x + a[k][j][3].y;
            c1.x += a[k][j][4].x + a[k][j][4].y;
            c1.y += a[k][j][5].x + a[k][j][5].y;
            c1.z += a[k][j][6].x + a[k][j][6].y;
            c1.w += a[k][j][7].x + a[k][j][7].y;
            ((f4v*)op)[0] = c0;
            ((f4v*)op)[1] = c1;
        }
    }
}

extern "C" void kernel_launch(void* const* d_in, const int* in_sizes, int n_in,
                              void* d_out, int out_size, void* d_ws, size_t ws_size,
                              hipStream_t stream) {
    const float* x    = (const float*)d_in[0];
    const float* arch = (const float*)d_in[1];
    const float* norms= (const float*)d_in[2];
    const int*   idx  = (const int*)d_in[3];
    const float* w3   = (const float*)d_in[4];
    const float* w5   = (const float*)d_in[5];
    const float* w7   = (const float*)d_in[6];
    const float* w1   = (const float*)d_in[7];
    const float* s3dw = (const float*)d_in[8];
    const float* s3pw = (const float*)d_in[9];
    const float* s5dw = (const float*)d_in[10];
    const float* s5pw = (const float*)d_in[11];
    const float* d3   = (const float*)d_in[12];
    const float* d5   = (const float*)d_in[13];
    float* out = (float*)d_out;

    const size_t S = (size_t)NB * CF * HW * HW;  // 16,777,216 floats
    float* st1 = (float*)d_ws;
    float* st2 = st1 + S;
    float* st3 = st2 + S;
    float* Wc  = st3 + S;                         // 10*64*64*81 floats
    float* sw  = Wc + (size_t)NEDGE * 64 * 64 * TAPS;

    softmax_kernel<<<1, 64, 0, stream>>>(arch, norms, sw);
    build_w<<<(NEDGE * 64 * 64 * TAPS) / 256, 256, 0, stream>>>(
        w3, w5, w7, w1, s3dw, s3pw, s5dw, s5pw, d3, d5, sw, Wc);

    float* states[5] = {(float*)x, st1, st2, st3, out};
    int e = 0;
    for (int node = 0; node < 4; ++node) {
        int ebase = node * (node + 1) / 2;
        pool_node<<<(int)(S / 256), 256, 0, stream>>>(
            states[0], states[1], states[2], states[3],
            states[node + 1], sw, ebase, node + 1);
        for (int i = 0; i <= node; ++i) {
            conv_edge<<<NB * 8, 256, 0, stream>>>(states[i], states[node + 1], Wc, idx, e);
            ++e;
        }
    }
}